// Round 17
// baseline (312.116 us; speedup 1.0000x reference)
//
#include <hip/hip_runtime.h>
#include <math.h>

#define TC 768      // text rows
#define DD 512      // feature dim
#define MM 430      // cache slots
#define MP 448      // padded slots
#define WNT 14      // write-path tiles of 32 slots
// per-scale row counts and offsets into concatenated index space
#define N0 65536
#define N1 16384
#define N2 4096
#define OFF1 65536
#define OFF2 81920
#define NTOT 86016
constexpr float kALPHA = 0.2f;
constexpr float kMOM   = 0.8f;

typedef short bf16x8 __attribute__((ext_vector_type(8)));
typedef float f32x4 __attribute__((ext_vector_type(4)));

// fragment-layout index (shorts) for a 16-slot tile, K-chunks of 32:
// frag(tile, col, k) = tile*16*K + ((k>>5)*64 + ((k>>3)&3)*16 + col)*8 + (k&7)
__device__ __forceinline__ size_t fragidx(int tile, int col, int k, int K) {
  return (size_t)tile * 16 * K + ((((k >> 5) * 64 + ((k >> 3) & 3) * 16 + col)) << 3) + (k & 7);
}

// ---------------- helpers ----------------
__device__ __forceinline__ float wave_reduce_sum(float v) {
#pragma unroll
  for (int o = 32; o > 0; o >>= 1) v += __shfl_down(v, o);
  return v;
}
__device__ __forceinline__ float wave_reduce_max(float v) {
#pragma unroll
  for (int o = 32; o > 0; o >>= 1) v = fmaxf(v, __shfl_down(v, o));
  return v;
}
__device__ __forceinline__ unsigned int fkey(float f) {
  unsigned int b = __float_as_uint(f);
  return (b & 0x80000000u) ? ~b : (b | 0x80000000u);
}
__device__ __forceinline__ float fdecode(unsigned int k) {
  return __uint_as_float((k & 0x80000000u) ? (k & 0x7FFFFFFFu) : ~k);
}
__device__ __forceinline__ unsigned short f2bf(float f) {
  unsigned int u = __float_as_uint(f);
  u += 0x7FFFu + ((u >> 16) & 1u);  // RNE
  return (unsigned short)(u >> 16);
}
__device__ __forceinline__ float bf2f(unsigned short u) {
  return __uint_as_float(((unsigned int)u) << 16);
}
// async global->LDS, 16B per lane (lds dest = wave-uniform base + lane*16)
__device__ __forceinline__ void gload_lds16(const unsigned short* g, unsigned short* l) {
  __builtin_amdgcn_global_load_lds(
      (const __attribute__((address_space(1))) void*)g,
      (__attribute__((address_space(3))) void*)l, 16, 0, 0);
}

// ---------------- fused prep: textB | wB | cacheB | init ----------------
// grid sections: [0,768) textB, [768,1280) wB, [1280,1728) cacheB, [1728,2588) init
__global__ __launch_bounds__(256) void k_prep(
    const float* __restrict__ text, const float* __restrict__ W,
    const float* __restrict__ cache,
    unsigned short* __restrict__ tb, float* __restrict__ invT,
    unsigned short* __restrict__ wb,
    unsigned short* __restrict__ cb, unsigned short* __restrict__ cbT,
    float* __restrict__ sums, float* __restrict__ outnc,
    int* __restrict__ cnt, unsigned int* __restrict__ colkey,
    float* __restrict__ out_loss, int* __restrict__ done) {
  const int b = blockIdx.x, tid = threadIdx.x;
  if (b < 768) {  // textB
    __shared__ float sred[8];
    const int c = b, lane = tid & 63, wid = tid >> 6;
    float x0 = text[(size_t)c * DD + tid];
    float x1 = text[(size_t)c * DD + 256 + tid];
    float ss = x0 * x0 + x1 * x1;
    ss = wave_reduce_sum(ss);
    if (lane == 0) sred[wid] = ss;
    __syncthreads();
    if (tid == 0) {
      float t = sred[0] + sred[1] + sred[2] + sred[3];
      invT[c] = 1.0f / fmaxf(sqrtf(t), 1e-12f);
    }
    const int rtile = c >> 4, colc = c & 15;
    tb[fragidx(rtile, colc, tid, DD)] = f2bf(x0);
    tb[fragidx(rtile, colc, tid + 256, DD)] = f2bf(x1);
  } else if (b < 1280) {  // wB
    const int j = b - 768;
    const int jt = j >> 4, colc = j & 15;
    float4 v = *(const float4*)(W + (size_t)j * 1024 + tid * 4);
    const float vv[4] = {v.x, v.y, v.z, v.w};
#pragma unroll
    for (int e = 0; e < 4; e++)
      wb[fragidx(jt, colc, tid * 4 + e, 1024)] = f2bf(vv[e]);
  } else if (b < 1728) {  // cacheB
    const int m = b - 1280;
    const int mt16 = m >> 4, colm = m & 15;
    for (int d = tid; d < DD; d += 256) {
      unsigned short v = (m < MM) ? f2bf(cache[(size_t)m * DD + d]) : (unsigned short)0;
      cb[fragidx(mt16, colm, d, DD)] = v;
      cbT[fragidx(d >> 4, d & 15, m, MP)] = v;
    }
  } else {  // init: zero sums (660480 f) then outnc (220160 f), 1024 f/block
    const int ib = b - 1728;
    const int idx = ib * 1024 + tid * 4;
    float4 z = make_float4(0.f, 0.f, 0.f, 0.f);
    if (idx < 3 * MM * DD) *(float4*)(sums + idx) = z;
    else *(float4*)(outnc + (idx - 3 * MM * DD)) = z;
    if (ib == 0) {
#pragma unroll
      for (int i = 0; i < 6; i++) {
        cnt[tid + i * 256] = 0;
        colkey[tid + i * 256] = 0u;
      }
      if (tid == 0) { out_loss[0] = 0.f; done[0] = 0; }
    }
  }
}

// ---------------- merged: write-path score (672 blocks) + read-path score (24) ----------------
// blocks [0,672): MFMA score over 3 scales, 512 thr = 8 waves, 128 rows/block,
//   TS=32 double-buffered LDS; XCD-chunked block swizzle for cb L2 residency.
//   Last write-score block to finish runs the 3-scale prefix scan inline.
// blocks [672,696): read-path score+softmax, 512 thr = 2 halves x 16 rows.
__global__ __launch_bounds__(512, 2) void k_score_plus(
    const float* __restrict__ img4, const float* __restrict__ img8,
    const float* __restrict__ img12, const unsigned short* __restrict__ cb,
    int* __restrict__ top1, float* __restrict__ topval,
    float* __restrict__ invn, unsigned int* __restrict__ colkey,
    int* __restrict__ cnt, int* __restrict__ woffs, int* __restrict__ done,
    const unsigned short* __restrict__ tb, const float* __restrict__ invT,
    unsigned short* __restrict__ pb) {
  __shared__ __align__(16) unsigned char smem[2 * 32 * DD * 2 + MP * 4];  // 67328 B
  __shared__ int lastBlk;
  const int braw = blockIdx.x;
  const int tid = threadIdx.x;
  const int lane = tid & 63;
  const int col = lane & 15, grp = lane >> 4;

  if (braw < 672) {
    // XCD-chunked swizzle (bijective: 672 = 8 * 84)
    const int b = (braw & 7) * 84 + (braw >> 3);
    // ---------- write-path score (r11 structure) ----------
    unsigned short* ldsB = (unsigned short*)smem;             // [2][32*DD]
    unsigned int* scol = (unsigned int*)(smem + 2 * 32 * DD * 2);
    const float* img;
    int n0, off, sc;
    if (b < 512)      { sc = 0; img = img4;  n0 = b * 128;         off = 0; }
    else if (b < 640) { sc = 1; img = img8;  n0 = (b - 512) * 128; off = OFF1; }
    else              { sc = 2; img = img12; n0 = (b - 640) * 128; off = OFF2; }
    const int w = tid >> 6;
    const int nw = n0 + w * 16;

    for (int i = tid; i < MP; i += 512) scol[i] = 0u;

#pragma unroll
    for (int i = 0; i < 4; i++)
      gload_lds16(cb + (i * 512 + tid) * 8, ldsB + (i * 512 + tid) * 8);

    bf16x8 afrag[16];
    float ss = 0.f;
    {
      const float* arow = img + (size_t)(nw + col) * DD + grp * 8;
#pragma unroll
      for (int kk = 0; kk < 16; kk++) {
        float4 f0 = *(const float4*)(arow + kk * 32);
        float4 f1 = *(const float4*)(arow + kk * 32 + 4);
        ss += f0.x * f0.x + f0.y * f0.y + f0.z * f0.z + f0.w * f0.w +
              f1.x * f1.x + f1.y * f1.y + f1.z * f1.z + f1.w * f1.w;
        bf16x8 a;
        a[0] = (short)f2bf(f0.x); a[1] = (short)f2bf(f0.y);
        a[2] = (short)f2bf(f0.z); a[3] = (short)f2bf(f0.w);
        a[4] = (short)f2bf(f1.x); a[5] = (short)f2bf(f1.y);
        a[6] = (short)f2bf(f1.z); a[7] = (short)f2bf(f1.w);
        afrag[kk] = a;
      }
    }
    ss += __shfl_xor(ss, 16);
    ss += __shfl_xor(ss, 32);
    const float inv = 1.0f / fmaxf(sqrtf(ss), 1e-12f);
    if (grp == 0) invn[off + nw + col] = inv;
    float invr[4];
#pragma unroll
    for (int i = 0; i < 4; i++) invr[i] = __shfl(inv, grp * 4 + i);

    float bestv[4];
    int besti[4];
#pragma unroll
    for (int i = 0; i < 4; i++) { bestv[i] = -1e30f; besti[i] = 0; }

    __syncthreads();  // tile 0 staged (vmcnt drained) + scol init visible

    for (int mt = 0; mt < WNT; mt++) {
      const int cur = mt & 1;
      if (mt + 1 < WNT) {
        const unsigned short* src = cb + (size_t)(mt + 1) * (32 * DD);
        unsigned short* dst = ldsB + (cur ^ 1) * (32 * DD);
#pragma unroll
        for (int i = 0; i < 4; i++)
          gload_lds16(src + (i * 512 + tid) * 8, dst + (i * 512 + tid) * 8);
      }
      // 8 independent MFMA chains (2 col-subtiles x 4 K-phases, depth 4)
      f32x4 acc[2][4];
#pragma unroll
      for (int c = 0; c < 2; c++)
#pragma unroll
        for (int e = 0; e < 4; e++) acc[c][e] = (f32x4){0.f, 0.f, 0.f, 0.f};
      const unsigned short* lb = ldsB + cur * (32 * DD);
#pragma unroll
      for (int kk = 0; kk < 16; kk++) {
        bf16x8 b0 = *(const bf16x8*)(lb + ((0 * 16 + kk) * 64 + lane) * 8);
        bf16x8 b1 = *(const bf16x8*)(lb + ((1 * 16 + kk) * 64 + lane) * 8);
        const int eo = kk & 3;
        acc[0][eo] = __builtin_amdgcn_mfma_f32_16x16x32_bf16(afrag[kk], b0, acc[0][eo], 0, 0, 0);
        acc[1][eo] = __builtin_amdgcn_mfma_f32_16x16x32_bf16(afrag[kk], b1, acc[1][eo], 0, 0, 0);
      }
#pragma unroll
      for (int c = 0; c < 2; c++) {
        const int gcol = mt * 32 + c * 16 + col;
        float colm = -1e30f;
#pragma unroll
        for (int i = 0; i < 4; i++) {
          float v = ((acc[c][0][i] + acc[c][1][i]) + (acc[c][2][i] + acc[c][3][i])) * invr[i];
          colm = fmaxf(colm, v);
          if (gcol < MM && v > bestv[i]) { bestv[i] = v; besti[i] = gcol; }
        }
        colm = fmaxf(colm, __shfl_xor(colm, 16));
        colm = fmaxf(colm, __shfl_xor(colm, 32));
        if (grp == 0 && gcol < MM) atomicMax(&scol[gcol], fkey(colm));
      }
      __syncthreads();
    }

#pragma unroll
    for (int i = 0; i < 4; i++) {
      float v = bestv[i];
      int idx = besti[i];
#pragma unroll
      for (int mask = 1; mask < 16; mask <<= 1) {
        float ov = __shfl_xor(v, mask);
        int oi = __shfl_xor(idx, mask);
        if (ov > v || (ov == v && oi < idx)) { v = ov; idx = oi; }
      }
      if (col == 0) {
        const int row = nw + grp * 4 + i;
        top1[off + row] = idx;
        topval[off + row] = v;
        atomicAdd(cnt + sc * 512 + idx, 1);
      }
    }
    __syncthreads();
    for (int i = tid; i < MM; i += 512) atomicMax(&colkey[sc * 512 + i], scol[i]);

    // ---- last-block-done ticket: the 672nd block runs the 3-scale prefix ----
    __syncthreads();
    __threadfence();
    if (tid == 0) lastBlk = (atomicAdd(done, 1) == 671);
    __syncthreads();
    if (lastBlk) {
      int* s = (int*)smem;  // alias (ldsB no longer needed)
      for (int sc2 = 0; sc2 < 3; sc2++) {
        int c = 0;
        if (tid < MM) c = atomicAdd(&cnt[sc2 * 512 + tid], 0);  // coherent read
        s[tid] = c;
        __syncthreads();
#pragma unroll
        for (int d = 1; d < 512; d <<= 1) {
          int v = (tid >= d) ? s[tid - d] : 0;
          __syncthreads();
          s[tid] += v;
          __syncthreads();
        }
        if (tid < MM) woffs[sc2 * 512 + tid] = s[tid] - c;
        __syncthreads();
      }
    }
  } else {
    // ---------- read-path score + softmax (2 independent 16-row halves) ----------
    const int h = tid >> 8;                // half: waves 0-3 / 4-7
    const int wh = (tid >> 6) & 3;         // wave within half
    const int rtile = (braw - 672) * 2 + h;  // [0,48)
    const int rowbase = rtile * 16;
    unsigned short (*sc16)[MP] = (unsigned short(*)[MP])smem + h * 16;  // [16][MP]

    bf16x8 afrag[16];
#pragma unroll
    for (int kk = 0; kk < 16; kk++)
      afrag[kk] = *(const bf16x8*)(tb + (size_t)rtile * 8192 + (kk * 64 + lane) * 8);
    float invv = invT[rowbase + col];
    float invr[4];
#pragma unroll
    for (int i = 0; i < 4; i++) invr[i] = __shfl(invv, grp * 4 + i);

    for (int j = 0; j < 7; j++) {
      const int mt = wh * 7 + j;
      const unsigned short* bbase = cb + (size_t)mt * 8192;
      f32x4 a0 = {0.f, 0.f, 0.f, 0.f}, a1 = {0.f, 0.f, 0.f, 0.f};
#pragma unroll
      for (int kk = 0; kk < 16; kk += 2) {
        bf16x8 b0 = *(const bf16x8*)(bbase + (kk * 64 + lane) * 8);
        bf16x8 b1 = *(const bf16x8*)(bbase + ((kk + 1) * 64 + lane) * 8);
        a0 = __builtin_amdgcn_mfma_f32_16x16x32_bf16(afrag[kk], b0, a0, 0, 0, 0);
        a1 = __builtin_amdgcn_mfma_f32_16x16x32_bf16(afrag[kk + 1], b1, a1, 0, 0, 0);
      }
      const int gcol = mt * 16 + col;
#pragma unroll
      for (int i = 0; i < 4; i++)
        sc16[grp * 4 + i][gcol] = f2bf((a0[i] + a1[i]) * invr[i]);
    }
    __syncthreads();

    for (int r0 = 0; r0 < 4; r0++) {
      const int rl = wh * 4 + r0;
      const unsigned short* srow = &sc16[rl][0];
      float mx = -1e30f;
      for (int m = lane; m < MM; m += 64) mx = fmaxf(mx, bf2f(srow[m]));
      mx = wave_reduce_max(mx);
      mx = __shfl(mx, 0);
      float sum = 0.f;
      for (int m = lane; m < MM; m += 64) sum += __expf(bf2f(srow[m]) - mx);
      sum = wave_reduce_sum(sum);
      sum = __shfl(sum, 0);
      const float invZ = 1.0f / sum;
      for (int m = lane; m < MP; m += 64) {
        float p = (m < MM) ? __expf(bf2f(srow[m]) - mx) * invZ : 0.f;
        pb[fragidx(rtile, rl, m, MP)] = f2bf(p);
      }
    }
  }
}

// ---------------- merged: sortidx (336) + fine_pv (48) ----------------
__global__ __launch_bounds__(256) void k_pv_sort(
    const int* __restrict__ top1, int* __restrict__ woffs,
    int* __restrict__ sorted,
    const unsigned short* __restrict__ pb, const unsigned short* __restrict__ cbT,
    unsigned short* __restrict__ fb) {
  const int b = blockIdx.x, tid = threadIdx.x;
  if (b < 336) {
    int sc, loc, off;
    if (b < 256)      { sc = 0; loc = b;        off = 0; }
    else if (b < 320) { sc = 1; loc = b - 256;  off = OFF1; }
    else              { sc = 2; loc = b - 320;  off = OFF2; }
    const int n = loc * 256 + tid;
    const int slot = top1[off + n];
    const int pos = atomicAdd(&woffs[sc * 512 + slot], 1);
    sorted[off + pos] = n;
  } else {
    const int fp = b - 336;               // [0,48)
    const int bx = fp % 12, by = fp / 12;
    const int w = tid >> 6, lane = tid & 63;
    const int col = lane & 15, grp = lane >> 4;
    const int rowbase = bx * 64 + w * 16;
    const int rtile = rowbase >> 4;
    const int dt0 = by * 8;
    bf16x8 afrag[14];
#pragma unroll
    for (int kk = 0; kk < 14; kk++)
      afrag[kk] = *(const bf16x8*)(pb + (size_t)rtile * 7168 + (kk * 64 + lane) * 8);
    for (int dt = dt0; dt < dt0 + 8; dt++) {
      f32x4 a0 = {0.f, 0.f, 0.f, 0.f}, a1 = {0.f, 0.f, 0.f, 0.f};
#pragma unroll
      for (int kk = 0; kk < 14; kk += 2) {
        bf16x8 b0 = *(const bf16x8*)(cbT + (size_t)dt * 7168 + (kk * 64 + lane) * 8);
        bf16x8 b1 = *(const bf16x8*)(cbT + (size_t)dt * 7168 + ((kk + 1) * 64 + lane) * 8);
        a0 = __builtin_amdgcn_mfma_f32_16x16x32_bf16(afrag[kk], b0, a0, 0, 0, 0);
        a1 = __builtin_amdgcn_mfma_f32_16x16x32_bf16(afrag[kk + 1], b1, a1, 0, 0, 0);
      }
#pragma unroll
      for (int i = 0; i < 4; i++) {
        const int d = dt * 16 + col;
        fb[fragidx(rtile, grp * 4 + i, d, DD)] = f2bf(a0[i] + a1[i]);
      }
    }
  }
}

// ---------------- merged: accum (672) + extractor (48) ----------------
__global__ __launch_bounds__(256) void k_ext_accum(
    const float* __restrict__ img4, const float* __restrict__ img8,
    const float* __restrict__ img12, const float* __restrict__ invn,
    const int* __restrict__ top1, const float* __restrict__ topval,
    const unsigned int* __restrict__ colkey, const int* __restrict__ sorted,
    float* __restrict__ sums,
    const unsigned short* __restrict__ tb, const unsigned short* __restrict__ fb,
    const unsigned short* __restrict__ wb, const float* __restrict__ text,
    float* __restrict__ out) {
  __shared__ int s_n[128];
  __shared__ int s_slot[128];
  __shared__ float s_w[128];
  const int braw = blockIdx.x, tid = threadIdx.x;
  if (braw < 672) {
    const int b = (braw & 7) * 84 + (braw >> 3);  // XCD-chunked swizzle
    const float* img;
    int r0, off, sc;
    if (b < 512)      { sc = 0; img = img4;  r0 = b * 128;         off = 0; }
    else if (b < 640) { sc = 1; img = img8;  r0 = (b - 512) * 128; off = OFF1; }
    else              { sc = 2; img = img12; r0 = (b - 640) * 128; off = OFF2; }
    float* sums_s = sums + (size_t)sc * MM * DD;
    if (tid < 128) {
      int n = sorted[off + r0 + tid];
      int sl = top1[off + n];
      s_n[tid] = n;
      s_slot[tid] = sl;
      s_w[tid] = __expf(topval[off + n] - fdecode(colkey[sc * 512 + sl])) * invn[off + n];
    }
    __syncthreads();
    float ax = 0.f, ay = 0.f;
    int cur = s_slot[0];
    for (int r = 0; r < 128; r++) {
      int sl = s_slot[r];
      if (sl != cur) {
        atomicAdd(&sums_s[(size_t)cur * DD + tid * 2], ax);
        atomicAdd(&sums_s[(size_t)cur * DD + tid * 2 + 1], ay);
        ax = 0.f; ay = 0.f; cur = sl;
      }
      const float2 v = *(const float2*)(img + (size_t)s_n[r] * DD + tid * 2);
      const float w = s_w[r];
      ax += w * v.x;
      ay += w * v.y;
    }
    atomicAdd(&sums_s[(size_t)cur * DD + tid * 2], ax);
    atomicAdd(&sums_s[(size_t)cur * DD + tid * 2 + 1], ay);
  } else {
    const int ea = braw - 672;            // [0,48)
    const int bx = ea % 12, by = ea / 12;
    const int w = tid >> 6, lane = tid & 63;
    const int col = lane & 15, grp = lane >> 4;
    const int rowbase = bx * 64 + w * 16;
    const int rtile = rowbase >> 4;
    const int jt0 = by * 8;
    bf16x8 afrag[32];
#pragma unroll
    for (int kk = 0; kk < 16; kk++)
      afrag[kk] = *(const bf16x8*)(tb + (size_t)rtile * 8192 + (kk * 64 + lane) * 8);
#pragma unroll
    for (int kk = 0; kk < 16; kk++)
      afrag[16 + kk] = *(const bf16x8*)(fb + (size_t)rtile * 8192 + (kk * 64 + lane) * 8);
    for (int jt = jt0; jt < jt0 + 8; jt++) {
      f32x4 a0 = {0.f, 0.f, 0.f, 0.f}, a1 = {0.f, 0.f, 0.f, 0.f};
#pragma unroll
      for (int kk = 0; kk < 32; kk += 2) {
        bf16x8 b0 = *(const bf16x8*)(wb + (size_t)jt * 16384 + (kk * 64 + lane) * 8);
        bf16x8 b1 = *(const bf16x8*)(wb + (size_t)jt * 16384 + ((kk + 1) * 64 + lane) * 8);
        a0 = __builtin_amdgcn_mfma_f32_16x16x32_bf16(afrag[kk], b0, a0, 0, 0, 0);
        a1 = __builtin_amdgcn_mfma_f32_16x16x32_bf16(afrag[kk + 1], b1, a1, 0, 0, 0);
      }
#pragma unroll
      for (int i = 0; i < 4; i++) {
        const int row = rowbase + grp * 4 + i;
        const int j = jt * 16 + col;
        out[(size_t)row * DD + j] = kALPHA * (a0[i] + a1[i]) + text[(size_t)row * DD + j];
      }
    }
  }
}

// ---------------- merged: upd (1290) + loss (768) ----------------
__global__ __launch_bounds__(256) void k_upd_loss(
    const float* __restrict__ cache, const float* __restrict__ sums,
    const int* __restrict__ cnt, float* __restrict__ outnc,
    const float* __restrict__ out, const float* __restrict__ text,
    float* __restrict__ out_loss) {
  __shared__ float sred[8];
  const int b = blockIdx.x, tid = threadIdx.x, lane = tid & 63, wid = tid >> 6;
  if (b < 3 * MM) {
    const int sc = b / MM, m = b % MM;
    const float* sums_s = sums + (size_t)sc * MM * DD;
    float c0 = cache[(size_t)m * DD + tid], c1 = cache[(size_t)m * DD + 256 + tid];
    float u0, u1;
    if (cnt[sc * 512 + m] > 0) {
      u0 = kMOM * c0 + (1.0f - kMOM) * sums_s[(size_t)m * DD + tid];
      u1 = kMOM * c1 + (1.0f - kMOM) * sums_s[(size_t)m * DD + 256 + tid];
    } else {
      u0 = c0; u1 = c1;
    }
    float ss = u0 * u0 + u1 * u1;
    ss = wave_reduce_sum(ss);
    if (lane == 0) sred[wid] = ss;
    __syncthreads();
    if (tid == 0) sred[0] = sred[0] + sred[1] + sred[2] + sred[3];
    __syncthreads();
    const float inv3 = (1.0f / 3.0f) / fmaxf(sqrtf(sred[0]), 1e-12f);
    atomicAdd(&outnc[(size_t)m * DD + tid], u0 * inv3);
    atomicAdd(&outnc[(size_t)m * DD + 256 + tid], u1 * inv3);
  } else {
    const int c = b - 3 * MM;
    float t0 = out[(size_t)c * DD + tid], t1 = out[(size_t)c * DD + 256 + tid];
    float ss = t0 * t0 + t1 * t1;
    ss = wave_reduce_sum(ss);
    if (lane == 0) sred[wid] = ss;
    __syncthreads();
    if (tid == 0) sred[0] = sred[0] + sred[1] + sred[2] + sred[3];
    __syncthreads();
    float inv = 1.0f / fmaxf(sqrtf(sred[0]), 1e-12f);
    float s = fabsf(t0 * inv - text[(size_t)c * DD + tid]) +
              fabsf(t1 * inv - text[(size_t)c * DD + 256 + tid]);
    s = wave_reduce_sum(s);
    __syncthreads();
    if (lane == 0) sred[wid] = s;
    __syncthreads();
    if (tid == 0)
      atomicAdd(out_loss, (sred[0] + sred[1] + sred[2] + sred[3]) / (float)(TC * DD));
  }
}

// ---------------- launch ----------------
extern "C" void kernel_launch(void* const* d_in, const int* in_sizes, int n_in,
                              void* d_out, int out_size, void* d_ws, size_t ws_size,
                              hipStream_t stream) {
  const float* text  = (const float*)d_in[0];
  const float* img4  = (const float*)d_in[1];
  const float* img8  = (const float*)d_in[2];
  const float* img12 = (const float*)d_in[3];
  const float* cache = (const float*)d_in[4];
  const float* W     = (const float*)d_in[5];
  float* out = (float*)d_out;
  float* out_loss = out + (size_t)TC * DD;       // index 393216
  float* out_nc   = out + (size_t)TC * DD + 1;   // 430*512 floats

  char* p = (char*)d_ws;
  float* invn          = (float*)p; p += NTOT * sizeof(float);
  int* top1            = (int*)p;   p += NTOT * sizeof(int);
  float* topval        = (float*)p; p += NTOT * sizeof(float);
  int* sorted          = (int*)p;   p += NTOT * sizeof(int);
  unsigned int* colkey = (unsigned int*)p; p += 3 * 512 * sizeof(unsigned int);
  float* sums          = (float*)p; p += (size_t)3 * MM * DD * sizeof(float);
  int* cnt             = (int*)p;   p += 3 * 512 * sizeof(int);
  int* woffs           = (int*)p;   p += 3 * 512 * sizeof(int);
  int* done            = (int*)p;   p += 256;
  unsigned short* cb   = (unsigned short*)p; p += (size_t)MP * DD * sizeof(unsigned short);
  unsigned short* cbT  = (unsigned short*)p; p += (size_t)DD * MP * sizeof(unsigned short);
  unsigned short* tb   = (unsigned short*)p; p += (size_t)TC * DD * sizeof(unsigned short);
  unsigned short* pb   = (unsigned short*)p; p += (size_t)TC * MP * sizeof(unsigned short);
  unsigned short* fb   = (unsigned short*)p; p += (size_t)TC * DD * sizeof(unsigned short);
  unsigned short* wb   = (unsigned short*)p; p += (size_t)DD * 1024 * sizeof(unsigned short);
  float* invT          = (float*)p; p += 1024 * sizeof(float);
  (void)in_sizes; (void)n_in; (void)out_size; (void)ws_size;

  // 1. fused prep (textB | wB | cacheB | init)
  k_prep<<<dim3(2588), dim3(256), 0, stream>>>(text, W, cache, tb, invT, wb,
                                               cb, cbT, sums, out_nc, cnt, colkey,
                                               out_loss, done);
  // 2. write-score (672, XCD-swizzled, inline prefix) + read-score (24)
  k_score_plus<<<dim3(696), dim3(512), 0, stream>>>(img4, img8, img12, cb,
                                                    top1, topval, invn, colkey, cnt,
                                                    woffs, done, tb, invT, pb);
  // 3. sortidx (336) + fine PV (48)
  k_pv_sort<<<dim3(384), dim3(256), 0, stream>>>(top1, woffs, sorted, pb, cbT, fb);
  // 4. accum (672, XCD-swizzled) + extractor (48)
  k_ext_accum<<<dim3(720), dim3(256), 0, stream>>>(img4, img8, img12, invn,
                                                   top1, topval, colkey, sorted, sums,
                                                   tb, fb, wb, text, out);
  // 5. momentum update (1290) + loss (768)
  k_upd_loss<<<dim3(2058), dim3(256), 0, stream>>>(cache, sums, cnt, out_nc,
                                                   out, text, out_loss);
}

// Round 18
// 222.639 us; speedup vs baseline: 1.4019x; 1.4019x over previous
//
#include <hip/hip_runtime.h>
#include <math.h>

#define TC 768      // text rows
#define DD 512      // feature dim
#define MM 430      // cache slots
#define MP 448      // padded slots
#define WNT 14      // write-path tiles of 32 slots
// per-scale row counts and offsets into concatenated index space
#define N0 65536
#define N1 16384
#define N2 4096
#define OFF1 65536
#define OFF2 81920
#define NTOT 86016
constexpr float kALPHA = 0.2f;
constexpr float kMOM   = 0.8f;

typedef short bf16x8 __attribute__((ext_vector_type(8)));
typedef float f32x4 __attribute__((ext_vector_type(4)));

// fragment-layout index (shorts) for a 16-slot tile, K-chunks of 32:
// frag(tile, col, k) = tile*16*K + ((k>>5)*64 + ((k>>3)&3)*16 + col)*8 + (k&7)
__device__ __forceinline__ size_t fragidx(int tile, int col, int k, int K) {
  return (size_t)tile * 16 * K + ((((k >> 5) * 64 + ((k >> 3) & 3) * 16 + col)) << 3) + (k & 7);
}

// ---------------- helpers ----------------
__device__ __forceinline__ float wave_reduce_sum(float v) {
#pragma unroll
  for (int o = 32; o > 0; o >>= 1) v += __shfl_down(v, o);
  return v;
}
__device__ __forceinline__ float wave_reduce_max(float v) {
#pragma unroll
  for (int o = 32; o > 0; o >>= 1) v = fmaxf(v, __shfl_down(v, o));
  return v;
}
__device__ __forceinline__ unsigned int fkey(float f) {
  unsigned int b = __float_as_uint(f);
  return (b & 0x80000000u) ? ~b : (b | 0x80000000u);
}
__device__ __forceinline__ float fdecode(unsigned int k) {
  return __uint_as_float((k & 0x80000000u) ? (k & 0x7FFFFFFFu) : ~k);
}
__device__ __forceinline__ unsigned short f2bf(float f) {
  unsigned int u = __float_as_uint(f);
  u += 0x7FFFu + ((u >> 16) & 1u);  // RNE
  return (unsigned short)(u >> 16);
}
__device__ __forceinline__ float bf2f(unsigned short u) {
  return __uint_as_float(((unsigned int)u) << 16);
}
// async global->LDS, 16B per lane (lds dest = wave-uniform base + lane*16)
__device__ __forceinline__ void gload_lds16(const unsigned short* g, unsigned short* l) {
  __builtin_amdgcn_global_load_lds(
      (const __attribute__((address_space(1))) void*)g,
      (__attribute__((address_space(3))) void*)l, 16, 0, 0);
}

// ---------------- fused prep: textB | wB | cacheB | init ----------------
// grid sections: [0,768) textB, [768,1280) wB, [1280,1728) cacheB, [1728,2588) init
__global__ __launch_bounds__(256) void k_prep(
    const float* __restrict__ text, const float* __restrict__ W,
    const float* __restrict__ cache,
    unsigned short* __restrict__ tb, float* __restrict__ invT,
    unsigned short* __restrict__ wb,
    unsigned short* __restrict__ cb, unsigned short* __restrict__ cbT,
    float* __restrict__ sums, float* __restrict__ outnc,
    int* __restrict__ cnt, unsigned int* __restrict__ colkey,
    float* __restrict__ out_loss) {
  const int b = blockIdx.x, tid = threadIdx.x;
  if (b < 768) {  // textB
    __shared__ float sred[8];
    const int c = b, lane = tid & 63, wid = tid >> 6;
    float x0 = text[(size_t)c * DD + tid];
    float x1 = text[(size_t)c * DD + 256 + tid];
    float ss = x0 * x0 + x1 * x1;
    ss = wave_reduce_sum(ss);
    if (lane == 0) sred[wid] = ss;
    __syncthreads();
    if (tid == 0) {
      float t = sred[0] + sred[1] + sred[2] + sred[3];
      invT[c] = 1.0f / fmaxf(sqrtf(t), 1e-12f);
    }
    const int rtile = c >> 4, colc = c & 15;
    tb[fragidx(rtile, colc, tid, DD)] = f2bf(x0);
    tb[fragidx(rtile, colc, tid + 256, DD)] = f2bf(x1);
  } else if (b < 1280) {  // wB
    const int j = b - 768;
    const int jt = j >> 4, colc = j & 15;
    float4 v = *(const float4*)(W + (size_t)j * 1024 + tid * 4);
    const float vv[4] = {v.x, v.y, v.z, v.w};
#pragma unroll
    for (int e = 0; e < 4; e++)
      wb[fragidx(jt, colc, tid * 4 + e, 1024)] = f2bf(vv[e]);
  } else if (b < 1728) {  // cacheB
    const int m = b - 1280;
    const int mt16 = m >> 4, colm = m & 15;
    for (int d = tid; d < DD; d += 256) {
      unsigned short v = (m < MM) ? f2bf(cache[(size_t)m * DD + d]) : (unsigned short)0;
      cb[fragidx(mt16, colm, d, DD)] = v;
      cbT[fragidx(d >> 4, d & 15, m, MP)] = v;
    }
  } else {  // init: zero sums (660480 f) then outnc (220160 f), 1024 f/block
    const int ib = b - 1728;
    const int idx = ib * 1024 + tid * 4;
    float4 z = make_float4(0.f, 0.f, 0.f, 0.f);
    if (idx < 3 * MM * DD) *(float4*)(sums + idx) = z;
    else *(float4*)(outnc + (idx - 3 * MM * DD)) = z;
    if (ib == 0) {
#pragma unroll
      for (int i = 0; i < 6; i++) {
        cnt[tid + i * 256] = 0;
        colkey[tid + i * 256] = 0u;
      }
      if (tid == 0) out_loss[0] = 0.f;
    }
  }
}

// ---------------- merged: write-path score (672 blocks) + read-path score (24) ----------------
// blocks [0,672): MFMA score over 3 scales, 512 thr = 8 waves, 128 rows/block,
//   TS=32 double-buffered LDS; XCD-chunked block swizzle for cb L2 residency.
// blocks [672,696): read-path score+softmax, 512 thr = 2 halves x 16 rows.
__global__ __launch_bounds__(512, 2) void k_score_plus(
    const float* __restrict__ img4, const float* __restrict__ img8,
    const float* __restrict__ img12, const unsigned short* __restrict__ cb,
    int* __restrict__ top1, float* __restrict__ topval,
    float* __restrict__ invn, unsigned int* __restrict__ colkey,
    int* __restrict__ cnt,
    const unsigned short* __restrict__ tb, const float* __restrict__ invT,
    unsigned short* __restrict__ pb) {
  __shared__ __align__(16) unsigned char smem[2 * 32 * DD * 2 + MP * 4];  // 67328 B
  const int braw = blockIdx.x;
  const int tid = threadIdx.x;
  const int lane = tid & 63;
  const int col = lane & 15, grp = lane >> 4;

  if (braw < 672) {
    // XCD-chunked swizzle (bijective: 672 = 8 * 84)
    const int b = (braw & 7) * 84 + (braw >> 3);
    // ---------- write-path score (r11 structure) ----------
    unsigned short* ldsB = (unsigned short*)smem;             // [2][32*DD]
    unsigned int* scol = (unsigned int*)(smem + 2 * 32 * DD * 2);
    const float* img;
    int n0, off, sc;
    if (b < 512)      { sc = 0; img = img4;  n0 = b * 128;         off = 0; }
    else if (b < 640) { sc = 1; img = img8;  n0 = (b - 512) * 128; off = OFF1; }
    else              { sc = 2; img = img12; n0 = (b - 640) * 128; off = OFF2; }
    const int w = tid >> 6;
    const int nw = n0 + w * 16;

    for (int i = tid; i < MP; i += 512) scol[i] = 0u;

#pragma unroll
    for (int i = 0; i < 4; i++)
      gload_lds16(cb + (i * 512 + tid) * 8, ldsB + (i * 512 + tid) * 8);

    bf16x8 afrag[16];
    float ss = 0.f;
    {
      const float* arow = img + (size_t)(nw + col) * DD + grp * 8;
#pragma unroll
      for (int kk = 0; kk < 16; kk++) {
        float4 f0 = *(const float4*)(arow + kk * 32);
        float4 f1 = *(const float4*)(arow + kk * 32 + 4);
        ss += f0.x * f0.x + f0.y * f0.y + f0.z * f0.z + f0.w * f0.w +
              f1.x * f1.x + f1.y * f1.y + f1.z * f1.z + f1.w * f1.w;
        bf16x8 a;
        a[0] = (short)f2bf(f0.x); a[1] = (short)f2bf(f0.y);
        a[2] = (short)f2bf(f0.z); a[3] = (short)f2bf(f0.w);
        a[4] = (short)f2bf(f1.x); a[5] = (short)f2bf(f1.y);
        a[6] = (short)f2bf(f1.z); a[7] = (short)f2bf(f1.w);
        afrag[kk] = a;
      }
    }
    ss += __shfl_xor(ss, 16);
    ss += __shfl_xor(ss, 32);
    const float inv = 1.0f / fmaxf(sqrtf(ss), 1e-12f);
    if (grp == 0) invn[off + nw + col] = inv;
    float invr[4];
#pragma unroll
    for (int i = 0; i < 4; i++) invr[i] = __shfl(inv, grp * 4 + i);

    float bestv[4];
    int besti[4];
#pragma unroll
    for (int i = 0; i < 4; i++) { bestv[i] = -1e30f; besti[i] = 0; }

    __syncthreads();  // tile 0 staged (vmcnt drained) + scol init visible

    for (int mt = 0; mt < WNT; mt++) {
      const int cur = mt & 1;
      if (mt + 1 < WNT) {
        const unsigned short* src = cb + (size_t)(mt + 1) * (32 * DD);
        unsigned short* dst = ldsB + (cur ^ 1) * (32 * DD);
#pragma unroll
        for (int i = 0; i < 4; i++)
          gload_lds16(src + (i * 512 + tid) * 8, dst + (i * 512 + tid) * 8);
      }
      f32x4 acc[2][2];
#pragma unroll
      for (int c = 0; c < 2; c++)
#pragma unroll
        for (int e = 0; e < 2; e++) acc[c][e] = (f32x4){0.f, 0.f, 0.f, 0.f};
      const unsigned short* lb = ldsB + cur * (32 * DD);
#pragma unroll
      for (int kk = 0; kk < 16; kk++) {
        bf16x8 b0 = *(const bf16x8*)(lb + ((0 * 16 + kk) * 64 + lane) * 8);
        bf16x8 b1 = *(const bf16x8*)(lb + ((1 * 16 + kk) * 64 + lane) * 8);
        const int eo = kk & 1;
        acc[0][eo] = __builtin_amdgcn_mfma_f32_16x16x32_bf16(afrag[kk], b0, acc[0][eo], 0, 0, 0);
        acc[1][eo] = __builtin_amdgcn_mfma_f32_16x16x32_bf16(afrag[kk], b1, acc[1][eo], 0, 0, 0);
      }
#pragma unroll
      for (int c = 0; c < 2; c++) {
        const int gcol = mt * 32 + c * 16 + col;
        float colm = -1e30f;
#pragma unroll
        for (int i = 0; i < 4; i++) {
          float v = (acc[c][0][i] + acc[c][1][i]) * invr[i];
          colm = fmaxf(colm, v);
          if (gcol < MM && v > bestv[i]) { bestv[i] = v; besti[i] = gcol; }
        }
        colm = fmaxf(colm, __shfl_xor(colm, 16));
        colm = fmaxf(colm, __shfl_xor(colm, 32));
        if (grp == 0 && gcol < MM) atomicMax(&scol[gcol], fkey(colm));
      }
      __syncthreads();
    }

#pragma unroll
    for (int i = 0; i < 4; i++) {
      float v = bestv[i];
      int idx = besti[i];
#pragma unroll
      for (int mask = 1; mask < 16; mask <<= 1) {
        float ov = __shfl_xor(v, mask);
        int oi = __shfl_xor(idx, mask);
        if (ov > v || (ov == v && oi < idx)) { v = ov; idx = oi; }
      }
      if (col == 0) {
        const int row = nw + grp * 4 + i;
        top1[off + row] = idx;
        topval[off + row] = v;
        atomicAdd(cnt + sc * 512 + idx, 1);
      }
    }
    __syncthreads();
    for (int i = tid; i < MM; i += 512) atomicMax(&colkey[sc * 512 + i], scol[i]);
  } else {
    // ---------- read-path score + softmax (2 independent 16-row halves) ----------
    const int h = tid >> 8;                // half: waves 0-3 / 4-7
    const int wh = (tid >> 6) & 3;         // wave within half
    const int rtile = (braw - 672) * 2 + h;  // [0,48)
    const int rowbase = rtile * 16;
    unsigned short (*sc16)[MP] = (unsigned short(*)[MP])smem + h * 16;  // [16][MP]

    bf16x8 afrag[16];
#pragma unroll
    for (int kk = 0; kk < 16; kk++)
      afrag[kk] = *(const bf16x8*)(tb + (size_t)rtile * 8192 + (kk * 64 + lane) * 8);
    float invv = invT[rowbase + col];
    float invr[4];
#pragma unroll
    for (int i = 0; i < 4; i++) invr[i] = __shfl(invv, grp * 4 + i);

    for (int j = 0; j < 7; j++) {
      const int mt = wh * 7 + j;
      const unsigned short* bbase = cb + (size_t)mt * 8192;
      f32x4 a0 = {0.f, 0.f, 0.f, 0.f}, a1 = {0.f, 0.f, 0.f, 0.f};
#pragma unroll
      for (int kk = 0; kk < 16; kk += 2) {
        bf16x8 b0 = *(const bf16x8*)(bbase + (kk * 64 + lane) * 8);
        bf16x8 b1 = *(const bf16x8*)(bbase + ((kk + 1) * 64 + lane) * 8);
        a0 = __builtin_amdgcn_mfma_f32_16x16x32_bf16(afrag[kk], b0, a0, 0, 0, 0);
        a1 = __builtin_amdgcn_mfma_f32_16x16x32_bf16(afrag[kk + 1], b1, a1, 0, 0, 0);
      }
      const int gcol = mt * 16 + col;
#pragma unroll
      for (int i = 0; i < 4; i++)
        sc16[grp * 4 + i][gcol] = f2bf((a0[i] + a1[i]) * invr[i]);
    }
    __syncthreads();

    for (int r0 = 0; r0 < 4; r0++) {
      const int rl = wh * 4 + r0;
      const unsigned short* srow = &sc16[rl][0];
      float mx = -1e30f;
      for (int m = lane; m < MM; m += 64) mx = fmaxf(mx, bf2f(srow[m]));
      mx = wave_reduce_max(mx);
      mx = __shfl(mx, 0);
      float sum = 0.f;
      for (int m = lane; m < MM; m += 64) sum += __expf(bf2f(srow[m]) - mx);
      sum = wave_reduce_sum(sum);
      sum = __shfl(sum, 0);
      const float invZ = 1.0f / sum;
      for (int m = lane; m < MP; m += 64) {
        float p = (m < MM) ? __expf(bf2f(srow[m]) - mx) * invZ : 0.f;
        pb[fragidx(rtile, rl, m, MP)] = f2bf(p);
      }
    }
  }
}

// exclusive prefix sum of cnt -> woffs (3 blocks, one per scale)
__global__ __launch_bounds__(512) void k_prefix(
    const int* __restrict__ cnt, int* __restrict__ woffs) {
  __shared__ int s[512];
  const int sc = blockIdx.x, t = threadIdx.x;
  const int c = (t < MM) ? cnt[sc * 512 + t] : 0;
  s[t] = c;
  __syncthreads();
#pragma unroll
  for (int d = 1; d < 512; d <<= 1) {
    int v = (t >= d) ? s[t - d] : 0;
    __syncthreads();
    s[t] += v;
    __syncthreads();
  }
  if (t < MM) woffs[sc * 512 + t] = s[t] - c;
}

// ---------------- merged: sortidx (336) + fine_pv (48) ----------------
__global__ __launch_bounds__(256) void k_pv_sort(
    const int* __restrict__ top1, int* __restrict__ woffs,
    int* __restrict__ sorted,
    const unsigned short* __restrict__ pb, const unsigned short* __restrict__ cbT,
    unsigned short* __restrict__ fb) {
  const int b = blockIdx.x, tid = threadIdx.x;
  if (b < 336) {
    int sc, loc, off;
    if (b < 256)      { sc = 0; loc = b;        off = 0; }
    else if (b < 320) { sc = 1; loc = b - 256;  off = OFF1; }
    else              { sc = 2; loc = b - 320;  off = OFF2; }
    const int n = loc * 256 + tid;
    const int slot = top1[off + n];
    const int pos = atomicAdd(&woffs[sc * 512 + slot], 1);
    sorted[off + pos] = n;
  } else {
    const int fp = b - 336;               // [0,48)
    const int bx = fp % 12, by = fp / 12;
    const int w = tid >> 6, lane = tid & 63;
    const int col = lane & 15, grp = lane >> 4;
    const int rowbase = bx * 64 + w * 16;
    const int rtile = rowbase >> 4;
    const int dt0 = by * 8;
    bf16x8 afrag[14];
#pragma unroll
    for (int kk = 0; kk < 14; kk++)
      afrag[kk] = *(const bf16x8*)(pb + (size_t)rtile * 7168 + (kk * 64 + lane) * 8);
    for (int dt = dt0; dt < dt0 + 8; dt++) {
      f32x4 a0 = {0.f, 0.f, 0.f, 0.f}, a1 = {0.f, 0.f, 0.f, 0.f};
#pragma unroll
      for (int kk = 0; kk < 14; kk += 2) {
        bf16x8 b0 = *(const bf16x8*)(cbT + (size_t)dt * 7168 + (kk * 64 + lane) * 8);
        bf16x8 b1 = *(const bf16x8*)(cbT + (size_t)dt * 7168 + ((kk + 1) * 64 + lane) * 8);
        a0 = __builtin_amdgcn_mfma_f32_16x16x32_bf16(afrag[kk], b0, a0, 0, 0, 0);
        a1 = __builtin_amdgcn_mfma_f32_16x16x32_bf16(afrag[kk + 1], b1, a1, 0, 0, 0);
      }
#pragma unroll
      for (int i = 0; i < 4; i++) {
        const int d = dt * 16 + col;
        fb[fragidx(rtile, grp * 4 + i, d, DD)] = f2bf(a0[i] + a1[i]);
      }
    }
  }
}

// ---------------- merged: accum (672) + extractor (48) ----------------
__global__ __launch_bounds__(256) void k_ext_accum(
    const float* __restrict__ img4, const float* __restrict__ img8,
    const float* __restrict__ img12, const float* __restrict__ invn,
    const int* __restrict__ top1, const float* __restrict__ topval,
    const unsigned int* __restrict__ colkey, const int* __restrict__ sorted,
    float* __restrict__ sums,
    const unsigned short* __restrict__ tb, const unsigned short* __restrict__ fb,
    const unsigned short* __restrict__ wb, const float* __restrict__ text,
    float* __restrict__ out) {
  __shared__ int s_n[128];
  __shared__ int s_slot[128];
  __shared__ float s_w[128];
  const int braw = blockIdx.x, tid = threadIdx.x;
  if (braw < 672) {
    const int b = (braw & 7) * 84 + (braw >> 3);  // XCD-chunked swizzle
    const float* img;
    int r0, off, sc;
    if (b < 512)      { sc = 0; img = img4;  r0 = b * 128;         off = 0; }
    else if (b < 640) { sc = 1; img = img8;  r0 = (b - 512) * 128; off = OFF1; }
    else              { sc = 2; img = img12; r0 = (b - 640) * 128; off = OFF2; }
    float* sums_s = sums + (size_t)sc * MM * DD;
    if (tid < 128) {
      int n = sorted[off + r0 + tid];
      int sl = top1[off + n];
      s_n[tid] = n;
      s_slot[tid] = sl;
      s_w[tid] = __expf(topval[off + n] - fdecode(colkey[sc * 512 + sl])) * invn[off + n];
    }
    __syncthreads();
    float ax = 0.f, ay = 0.f;
    int cur = s_slot[0];
    for (int r = 0; r < 128; r++) {
      int sl = s_slot[r];
      if (sl != cur) {
        atomicAdd(&sums_s[(size_t)cur * DD + tid * 2], ax);
        atomicAdd(&sums_s[(size_t)cur * DD + tid * 2 + 1], ay);
        ax = 0.f; ay = 0.f; cur = sl;
      }
      const float2 v = *(const float2*)(img + (size_t)s_n[r] * DD + tid * 2);
      const float w = s_w[r];
      ax += w * v.x;
      ay += w * v.y;
    }
    atomicAdd(&sums_s[(size_t)cur * DD + tid * 2], ax);
    atomicAdd(&sums_s[(size_t)cur * DD + tid * 2 + 1], ay);
  } else {
    const int ea = braw - 672;            // [0,48)
    const int bx = ea % 12, by = ea / 12;
    const int w = tid >> 6, lane = tid & 63;
    const int col = lane & 15, grp = lane >> 4;
    const int rowbase = bx * 64 + w * 16;
    const int rtile = rowbase >> 4;
    const int jt0 = by * 8;
    bf16x8 afrag[32];
#pragma unroll
    for (int kk = 0; kk < 16; kk++)
      afrag[kk] = *(const bf16x8*)(tb + (size_t)rtile * 8192 + (kk * 64 + lane) * 8);
#pragma unroll
    for (int kk = 0; kk < 16; kk++)
      afrag[16 + kk] = *(const bf16x8*)(fb + (size_t)rtile * 8192 + (kk * 64 + lane) * 8);
    for (int jt = jt0; jt < jt0 + 8; jt++) {
      f32x4 a0 = {0.f, 0.f, 0.f, 0.f}, a1 = {0.f, 0.f, 0.f, 0.f};
#pragma unroll
      for (int kk = 0; kk < 32; kk += 2) {
        bf16x8 b0 = *(const bf16x8*)(wb + (size_t)jt * 16384 + (kk * 64 + lane) * 8);
        bf16x8 b1 = *(const bf16x8*)(wb + (size_t)jt * 16384 + ((kk + 1) * 64 + lane) * 8);
        a0 = __builtin_amdgcn_mfma_f32_16x16x32_bf16(afrag[kk], b0, a0, 0, 0, 0);
        a1 = __builtin_amdgcn_mfma_f32_16x16x32_bf16(afrag[kk + 1], b1, a1, 0, 0, 0);
      }
#pragma unroll
      for (int i = 0; i < 4; i++) {
        const int row = rowbase + grp * 4 + i;
        const int j = jt * 16 + col;
        out[(size_t)row * DD + j] = kALPHA * (a0[i] + a1[i]) + text[(size_t)row * DD + j];
      }
    }
  }
}

// ---------------- merged: upd (1290) + loss (768) ----------------
__global__ __launch_bounds__(256) void k_upd_loss(
    const float* __restrict__ cache, const float* __restrict__ sums,
    const int* __restrict__ cnt, float* __restrict__ outnc,
    const float* __restrict__ out, const float* __restrict__ text,
    float* __restrict__ out_loss) {
  __shared__ float sred[8];
  const int b = blockIdx.x, tid = threadIdx.x, lane = tid & 63, wid = tid >> 6;
  if (b < 3 * MM) {
    const int sc = b / MM, m = b % MM;
    const float* sums_s = sums + (size_t)sc * MM * DD;
    float c0 = cache[(size_t)m * DD + tid], c1 = cache[(size_t)m * DD + 256 + tid];
    float u0, u1;
    if (cnt[sc * 512 + m] > 0) {
      u0 = kMOM * c0 + (1.0f - kMOM) * sums_s[(size_t)m * DD + tid];
      u1 = kMOM * c1 + (1.0f - kMOM) * sums_s[(size_t)m * DD + 256 + tid];
    } else {
      u0 = c0; u1 = c1;
    }
    float ss = u0 * u0 + u1 * u1;
    ss = wave_reduce_sum(ss);
    if (lane == 0) sred[wid] = ss;
    __syncthreads();
    if (tid == 0) sred[0] = sred[0] + sred[1] + sred[2] + sred[3];
    __syncthreads();
    const float inv3 = (1.0f / 3.0f) / fmaxf(sqrtf(sred[0]), 1e-12f);
    atomicAdd(&outnc[(size_t)m * DD + tid], u0 * inv3);
    atomicAdd(&outnc[(size_t)m * DD + 256 + tid], u1 * inv3);
  } else {
    const int c = b - 3 * MM;
    float t0 = out[(size_t)c * DD + tid], t1 = out[(size_t)c * DD + 256 + tid];
    float ss = t0 * t0 + t1 * t1;
    ss = wave_reduce_sum(ss);
    if (lane == 0) sred[wid] = ss;
    __syncthreads();
    if (tid == 0) sred[0] = sred[0] + sred[1] + sred[2] + sred[3];
    __syncthreads();
    float inv = 1.0f / fmaxf(sqrtf(sred[0]), 1e-12f);
    float s = fabsf(t0 * inv - text[(size_t)c * DD + tid]) +
              fabsf(t1 * inv - text[(size_t)c * DD + 256 + tid]);
    s = wave_reduce_sum(s);
    __syncthreads();
    if (lane == 0) sred[wid] = s;
    __syncthreads();
    if (tid == 0)
      atomicAdd(out_loss, (sred[0] + sred[1] + sred[2] + sred[3]) / (float)(TC * DD));
  }
}

// ---------------- launch ----------------
extern "C" void kernel_launch(void* const* d_in, const int* in_sizes, int n_in,
                              void* d_out, int out_size, void* d_ws, size_t ws_size,
                              hipStream_t stream) {
  const float* text  = (const float*)d_in[0];
  const float* img4  = (const float*)d_in[1];
  const float* img8  = (const float*)d_in[2];
  const float* img12 = (const float*)d_in[3];
  const float* cache = (const float*)d_in[4];
  const float* W     = (const float*)d_in[5];
  float* out = (float*)d_out;
  float* out_loss = out + (size_t)TC * DD;       // index 393216
  float* out_nc   = out + (size_t)TC * DD + 1;   // 430*512 floats

  char* p = (char*)d_ws;
  float* invn          = (float*)p; p += NTOT * sizeof(float);
  int* top1            = (int*)p;   p += NTOT * sizeof(int);
  float* topval        = (float*)p; p += NTOT * sizeof(float);
  int* sorted          = (int*)p;   p += NTOT * sizeof(int);
  unsigned int* colkey = (unsigned int*)p; p += 3 * 512 * sizeof(unsigned int);
  float* sums          = (float*)p; p += (size_t)3 * MM * DD * sizeof(float);
  int* cnt             = (int*)p;   p += 3 * 512 * sizeof(int);
  int* woffs           = (int*)p;   p += 3 * 512 * sizeof(int);
  unsigned short* cb   = (unsigned short*)p; p += (size_t)MP * DD * sizeof(unsigned short);
  unsigned short* cbT  = (unsigned short*)p; p += (size_t)DD * MP * sizeof(unsigned short);
  unsigned short* tb   = (unsigned short*)p; p += (size_t)TC * DD * sizeof(unsigned short);
  unsigned short* pb   = (unsigned short*)p; p += (size_t)TC * MP * sizeof(unsigned short);
  unsigned short* fb   = (unsigned short*)p; p += (size_t)TC * DD * sizeof(unsigned short);
  unsigned short* wb   = (unsigned short*)p; p += (size_t)DD * 1024 * sizeof(unsigned short);
  float* invT          = (float*)p; p += 1024 * sizeof(float);
  (void)in_sizes; (void)n_in; (void)out_size; (void)ws_size;

  // 1. fused prep (textB | wB | cacheB | init)
  k_prep<<<dim3(2588), dim3(256), 0, stream>>>(text, W, cache, tb, invT, wb,
                                               cb, cbT, sums, out_nc, cnt, colkey,
                                               out_loss);
  // 2. write-score (672, XCD-swizzled) + read-score (24)
  k_score_plus<<<dim3(696), dim3(512), 0, stream>>>(img4, img8, img12, cb,
                                                    top1, topval, invn, colkey, cnt,
                                                    tb, invT, pb);
  // 3. per-slot prefix sums
  k_prefix<<<dim3(3), dim3(512), 0, stream>>>(cnt, woffs);
  // 4. sortidx (336) + fine PV (48)
  k_pv_sort<<<dim3(384), dim3(256), 0, stream>>>(top1, woffs, sorted, pb, cbT, fb);
  // 5. accum (672, XCD-swizzled) + extractor (48)
  k_ext_accum<<<dim3(720), dim3(256), 0, stream>>>(img4, img8, img12, invn,
                                                   top1, topval, colkey, sorted, sums,
                                                   tb, fb, wb, text, out);
  // 6. momentum update (1290) + loss (768)
  k_upd_loss<<<dim3(2058), dim3(256), 0, stream>>>(cache, sums, cnt, out_nc,
                                                   out, text, out_loss);
}